// Round 2
// baseline (553.017 us; speedup 1.0000x reference)
//
#include <hip/hip_runtime.h>

// CompGraphConv: comp_h = n_feats[src] - r_feats[etype]
//                h_e    = (etype < num_rels/2 ? W_I : W_O) comp_h + b
//                n_out[v] = mean_{e: dst=e -> v} h_e
//                r_out    = r_feats @ W_R^T + b_R
//
// Restructured: scatter-add comp_h into per-node accI/accO (by branch),
// count degrees, then one matvec per node:
//   out[v] = (W_I accI[v] + cI b_I + W_O accO[v] + cO b_O) / max(cI+cO, 1)

#define DIM 64

__global__ void zero_ws_kernel(float* __restrict__ ws, long long n) {
    long long i = (long long)blockIdx.x * blockDim.x + threadIdx.x;
    long long stride = (long long)gridDim.x * blockDim.x;
    for (; i < n; i += stride) ws[i] = 0.0f;
}

__global__ __launch_bounds__(256) void edge_scatter_kernel(
    const float* __restrict__ n_feats,
    const float* __restrict__ r_feats,
    const int* __restrict__ src,
    const int* __restrict__ dst,
    const int* __restrict__ etype,
    const int* __restrict__ num_rels,
    float* __restrict__ accI,
    float* __restrict__ accO,
    int* __restrict__ cntI,
    int* __restrict__ cntO,
    int E)
{
    long long idx = (long long)blockIdx.x * blockDim.x + threadIdx.x;
    int e = (int)(idx >> 6);
    int d = (int)(idx & 63);
    if (e >= E) return;

    int s = src[e];
    int v = dst[e];
    int t = etype[e];
    int half = num_rels[0] >> 1;

    float comp = n_feats[(size_t)s * DIM + d] - r_feats[(size_t)t * DIM + d];

    if (t < half) {
        atomicAdd(&accI[(size_t)v * DIM + d], comp);
        if (d == 0) atomicAdd(&cntI[v], 1);
    } else {
        atomicAdd(&accO[(size_t)v * DIM + d], comp);
        if (d == 0) atomicAdd(&cntO[v], 1);
    }
}

// 4 nodes per 256-thread block; one wave (64 lanes) per node.
__global__ __launch_bounds__(256) void node_out_kernel(
    const float* __restrict__ accI,
    const float* __restrict__ accO,
    const int* __restrict__ cntI,
    const int* __restrict__ cntO,
    const float* __restrict__ W_I_w,
    const float* __restrict__ W_I_b,
    const float* __restrict__ W_O_w,
    const float* __restrict__ W_O_b,
    float* __restrict__ out,
    int N)
{
    // W stored transposed in LDS: WT[d*64 + j] = W[j*64 + d], so the
    // inner loop reads WT[d*64 + lane] -> lane-consecutive, conflict-free.
    __shared__ float WIt[DIM * DIM];
    __shared__ float WOt[DIM * DIM];
    __shared__ float rowI[4][DIM];
    __shared__ float rowO[4][DIM];

    int tid = threadIdx.x;
    for (int i = tid; i < DIM * DIM; i += 256) {
        int j = i >> 6;
        int d = i & 63;
        WIt[d * DIM + j] = W_I_w[i];
        WOt[d * DIM + j] = W_O_w[i];
    }

    int wave = tid >> 6;   // 0..3
    int lane = tid & 63;   // output feature j
    int v = blockIdx.x * 4 + wave;

    float aI = 0.0f, aO = 0.0f;
    if (v < N) {
        aI = accI[(size_t)v * DIM + lane];
        aO = accO[(size_t)v * DIM + lane];
    }
    rowI[wave][lane] = aI;
    rowO[wave][lane] = aO;
    __syncthreads();

    if (v < N) {
        int cI = cntI[v];
        int cO = cntO[v];
        float sum = (float)cI * W_I_b[lane] + (float)cO * W_O_b[lane];
        #pragma unroll
        for (int d = 0; d < DIM; ++d) {
            sum += WIt[d * DIM + lane] * rowI[wave][d]
                 + WOt[d * DIM + lane] * rowO[wave][d];
        }
        int deg = cI + cO;
        float inv = 1.0f / (float)(deg > 1 ? deg : 1);
        out[(size_t)v * DIM + lane] = sum * inv;
    }
}

// r_out = r_feats @ W_R^T + b_R ; 4 rows per 256-thread block.
__global__ __launch_bounds__(256) void rel_out_kernel(
    const float* __restrict__ r_feats,
    const float* __restrict__ W_R_w,
    const float* __restrict__ W_R_b,
    float* __restrict__ out,
    int R)
{
    __shared__ float WRt[DIM * DIM];
    __shared__ float row[4][DIM];

    int tid = threadIdx.x;
    for (int i = tid; i < DIM * DIM; i += 256) {
        int j = i >> 6;
        int d = i & 63;
        WRt[d * DIM + j] = W_R_w[i];
    }

    int wave = tid >> 6;
    int lane = tid & 63;
    int r = blockIdx.x * 4 + wave;

    float a = 0.0f;
    if (r < R) a = r_feats[(size_t)r * DIM + lane];
    row[wave][lane] = a;
    __syncthreads();

    if (r < R) {
        float sum = W_R_b[lane];
        #pragma unroll
        for (int d = 0; d < DIM; ++d) {
            sum += WRt[d * DIM + lane] * row[wave][d];
        }
        out[(size_t)r * DIM + lane] = sum;
    }
}

extern "C" void kernel_launch(void* const* d_in, const int* in_sizes, int n_in,
                              void* d_out, int out_size, void* d_ws, size_t ws_size,
                              hipStream_t stream) {
    const float* n_feats  = (const float*)d_in[0];
    const float* r_feats  = (const float*)d_in[1];
    const float* W_I_w    = (const float*)d_in[2];
    const float* W_I_b    = (const float*)d_in[3];
    const float* W_O_w    = (const float*)d_in[4];
    const float* W_O_b    = (const float*)d_in[5];
    const float* W_R_w    = (const float*)d_in[6];
    const float* W_R_b    = (const float*)d_in[7];
    const int*   src      = (const int*)d_in[8];
    const int*   dst      = (const int*)d_in[9];
    const int*   etype    = (const int*)d_in[10];
    const int*   num_rels = (const int*)d_in[11];

    const int N = in_sizes[0] / DIM;
    const int R = in_sizes[1] / DIM;
    const int E = in_sizes[8];

    // Workspace layout: accI [N*64 f32] | accO [N*64 f32] | cntI [N i32] | cntO [N i32]
    float* accI = (float*)d_ws;
    float* accO = accI + (size_t)N * DIM;
    int*   cntI = (int*)(accO + (size_t)N * DIM);
    int*   cntO = cntI + N;

    long long zero_words = (long long)N * DIM * 2 + 2LL * N;
    zero_ws_kernel<<<2048, 256, 0, stream>>>((float*)d_ws, zero_words);

    long long edge_threads = (long long)E * DIM;
    int edge_blocks = (int)((edge_threads + 255) / 256);
    edge_scatter_kernel<<<edge_blocks, 256, 0, stream>>>(
        n_feats, r_feats, src, dst, etype, num_rels,
        accI, accO, cntI, cntO, E);

    float* n_out = (float*)d_out;
    float* r_out = n_out + (size_t)N * DIM;

    int node_blocks = (N + 3) / 4;
    node_out_kernel<<<node_blocks, 256, 0, stream>>>(
        accI, accO, cntI, cntO, W_I_w, W_I_b, W_O_w, W_O_b, n_out, N);

    int rel_blocks = (R + 3) / 4;
    rel_out_kernel<<<rel_blocks, 256, 0, stream>>>(
        r_feats, W_R_w, W_R_b, r_out, R);
}

// Round 4
// 509.699 us; speedup vs baseline: 1.0850x; 1.0850x over previous
//
#include <hip/hip_runtime.h>

// CompGraphConv via CSR-by-dst + fused gather/matvec:
//   1. zero hist/cur
//   2. hist[v] = in-degree
//   3. rowptr = exclusive_scan(hist)        (single 1024-thread block)
//   4. es[rowptr[v] + k] = (src, etype)     (counting-sort scatter)
//   5. per-node wave: acc{I,O} = sum of comp vectors (registers),
//      then out[v] = (W_I accI + cI b_I + W_O accO + cO b_O)/max(deg,1)
//   6. r_out = r_feats @ W_R^T + b_R

#define DIM 64

__global__ void zero_int_kernel(int* __restrict__ p, int n) {
    int i = blockIdx.x * blockDim.x + threadIdx.x;
    if (i < n) p[i] = 0;
}

__global__ __launch_bounds__(256) void hist_kernel(
    const int* __restrict__ dst, int* __restrict__ hist, int E)
{
    int e = blockIdx.x * blockDim.x + threadIdx.x;
    if (e < E) atomicAdd(&hist[dst[e]], 1);
}

// Exclusive scan of hist[0..N) -> rowptr[0..N]; rowptr[N] = total.
__global__ __launch_bounds__(1024) void scan_kernel(
    const int* __restrict__ hist, int* __restrict__ rowptr, int N)
{
    __shared__ int part[1024];
    int tid = threadIdx.x;
    int chunk = (N + 1023) / 1024;
    int lo = tid * chunk;
    int hi = lo + chunk; if (hi > N) hi = N;

    int s = 0;
    for (int i = lo; i < hi; ++i) s += hist[i];
    part[tid] = s;
    __syncthreads();

    // Hillis-Steele inclusive scan (read, sync, write, sync)
    for (int off = 1; off < 1024; off <<= 1) {
        int t = (tid >= off) ? part[tid - off] : 0;
        __syncthreads();
        part[tid] += t;
        __syncthreads();
    }

    int run = part[tid] - s;   // exclusive prefix for this chunk
    for (int i = lo; i < hi; ++i) { rowptr[i] = run; run += hist[i]; }
    if (tid == 1023) rowptr[N] = part[1023];
}

__global__ __launch_bounds__(256) void scatter_kernel(
    const int* __restrict__ src, const int* __restrict__ dst,
    const int* __restrict__ etype, const int* __restrict__ rowptr,
    int* __restrict__ cur, int2* __restrict__ es, int E)
{
    int e = blockIdx.x * blockDim.x + threadIdx.x;
    if (e >= E) return;
    int v = dst[e];
    int pos = rowptr[v] + atomicAdd(&cur[v], 1);
    es[pos] = make_int2(src[e], etype[e]);
}

// 16 nodes per 1024-thread block; one wave (64 lanes) per node.
// Lane = feature index during gather, output feature during matvec.
__global__ __launch_bounds__(1024) void node_fused_kernel(
    const float* __restrict__ n_feats,
    const float* __restrict__ r_feats,
    const int* __restrict__ rowptr,
    const int2* __restrict__ es,
    const float* __restrict__ W_I_w, const float* __restrict__ W_I_b,
    const float* __restrict__ W_O_w, const float* __restrict__ W_O_b,
    const int* __restrict__ num_rels,
    float* __restrict__ out, int N)
{
    // Transposed weights in LDS: WT[d*64+j] = W[j*64+d] -> matvec inner
    // loop reads WT[d*64+lane]: lane-consecutive, conflict-free.
    __shared__ float WIt[DIM * DIM];
    __shared__ float WOt[DIM * DIM];
    __shared__ float rowI[16][DIM];
    __shared__ float rowO[16][DIM];

    int tid = threadIdx.x;
    for (int i = tid; i < DIM * DIM; i += 1024) {
        int j = i >> 6, d = i & 63;
        WIt[d * DIM + j] = W_I_w[i];
        WOt[d * DIM + j] = W_O_w[i];
    }

    int wave = tid >> 6;     // 0..15
    int lane = tid & 63;     // feature index
    int v = blockIdx.x * 16 + wave;
    int half = num_rels[0] >> 1;

    float aI = 0.0f, aO = 0.0f;
    int cI = 0, deg = 0;
    if (v < N) {
        int lo = rowptr[v], hi = rowptr[v + 1];
        deg = hi - lo;
        for (int i = lo; i < hi; ++i) {
            int2 st = es[i];                       // wave-uniform broadcast
            float c = n_feats[(size_t)st.x * DIM + lane]
                    - r_feats[(size_t)st.y * DIM + lane];
            if (st.y < half) { aI += c; ++cI; }
            else             { aO += c; }
        }
    }
    rowI[wave][lane] = aI;
    rowO[wave][lane] = aO;
    __syncthreads();   // covers weight staging + row staging

    if (v < N) {
        int cO = deg - cI;
        float sum = (float)cI * W_I_b[lane] + (float)cO * W_O_b[lane];
        #pragma unroll
        for (int d = 0; d < DIM; ++d) {
            sum += WIt[d * DIM + lane] * rowI[wave][d]
                 + WOt[d * DIM + lane] * rowO[wave][d];
        }
        out[(size_t)v * DIM + lane] = sum / (float)(deg > 1 ? deg : 1);
    }
}

// r_out = r_feats @ W_R^T + b_R ; 4 rows per 256-thread block.
__global__ __launch_bounds__(256) void rel_out_kernel(
    const float* __restrict__ r_feats,
    const float* __restrict__ W_R_w,
    const float* __restrict__ W_R_b,
    float* __restrict__ out, int R)
{
    __shared__ float WRt[DIM * DIM];
    __shared__ float row[4][DIM];

    int tid = threadIdx.x;
    for (int i = tid; i < DIM * DIM; i += 256) {
        int j = i >> 6, d = i & 63;
        WRt[d * DIM + j] = W_R_w[i];
    }

    int wave = tid >> 6, lane = tid & 63;
    int r = blockIdx.x * 4 + wave;

    float a = 0.0f;
    if (r < R) a = r_feats[(size_t)r * DIM + lane];
    row[wave][lane] = a;
    __syncthreads();

    if (r < R) {
        float sum = W_R_b[lane];
        #pragma unroll
        for (int d = 0; d < DIM; ++d)
            sum += WRt[d * DIM + lane] * row[wave][d];
        out[(size_t)r * DIM + lane] = sum;
    }
}

extern "C" void kernel_launch(void* const* d_in, const int* in_sizes, int n_in,
                              void* d_out, int out_size, void* d_ws, size_t ws_size,
                              hipStream_t stream) {
    const float* n_feats  = (const float*)d_in[0];
    const float* r_feats  = (const float*)d_in[1];
    const float* W_I_w    = (const float*)d_in[2];
    const float* W_I_b    = (const float*)d_in[3];
    const float* W_O_w    = (const float*)d_in[4];
    const float* W_O_b    = (const float*)d_in[5];
    const float* W_R_w    = (const float*)d_in[6];
    const float* W_R_b    = (const float*)d_in[7];
    const int*   src      = (const int*)d_in[8];
    const int*   dst      = (const int*)d_in[9];
    const int*   etype    = (const int*)d_in[10];
    const int*   num_rels = (const int*)d_in[11];

    const int N = in_sizes[0] / DIM;
    const int R = in_sizes[1] / DIM;
    const int E = in_sizes[8];

    // ws layout: es [E int2] | hist [N] | cur [N] | rowptr [N+1]
    int2* es     = (int2*)d_ws;
    int*  hist   = (int*)(es + (size_t)E);
    int*  cur    = hist + N;
    int*  rowptr = cur + N;

    // zero hist+cur (contiguous 2N ints)
    int zn = 2 * N;
    zero_int_kernel<<<(zn + 255) / 256, 256, 0, stream>>>(hist, zn);

    hist_kernel<<<(E + 255) / 256, 256, 0, stream>>>(dst, hist, E);

    scan_kernel<<<1, 1024, 0, stream>>>(hist, rowptr, N);

    scatter_kernel<<<(E + 255) / 256, 256, 0, stream>>>(
        src, dst, etype, rowptr, cur, es, E);

    float* n_out = (float*)d_out;
    float* r_out = n_out + (size_t)N * DIM;

    int node_blocks = (N + 15) / 16;
    node_fused_kernel<<<node_blocks, 1024, 0, stream>>>(
        n_feats, r_feats, rowptr, es,
        W_I_w, W_I_b, W_O_w, W_O_b, num_rels, n_out, N);

    rel_out_kernel<<<(R + 3) / 4, 256, 0, stream>>>(
        r_feats, W_R_w, W_R_b, r_out, R);
}

// Round 5
// 293.278 us; speedup vs baseline: 1.8856x; 1.7379x over previous
//
#include <hip/hip_runtime.h>

// CompGraphConv via CSR-by-dst + fused gather/matvec (v2: ILP + conflict-free LDS)
//   zero -> hist -> scan(1 block) -> scatter(counting sort) -> node_fused(+rel fused)
//
// node_fused v2:
//  - 8 nodes/block (512 thr, 1 wave/node); rel rows handled by trailing blocks
//  - gather: lane = float2 of features (fl=lane&31); half-wave h=lane>>5 takes
//    edges lo+h, lo+h+2, ... ; manual 4x unroll (8 edges in flight), branchless
//    select -> breaks the es->feat dependent-latency chain that bound v1
//  - weights in LDS row-major padded (W[j*WPAD+d], WPAD=68): staging stores are
//    lane-consecutive (conflict-free), matvec reads ds_read_b128 with bank
//    rotation (4j+d)%32 -> pure-BW, no conflict (v1 had 2.5e7 conflicts)

#define DIM 64
#define NPB 8          // nodes (or rel rows) per block
#define WPAD 68        // row stride of LDS weight tiles (pad 64 -> 68)
#define SCAN_CHUNK 52  // supports N <= 52*1024 = 53248 (N = 50000 here)

__global__ void zero_int_kernel(int* __restrict__ p, int n) {
    int i = blockIdx.x * blockDim.x + threadIdx.x;
    if (i < n) p[i] = 0;
}

__global__ __launch_bounds__(256) void hist_kernel(
    const int* __restrict__ dst, int* __restrict__ hist, int E)
{
    int e4 = (blockIdx.x * blockDim.x + threadIdx.x) * 4;
    if (e4 + 3 < E) {
        int4 q = *(const int4*)&dst[e4];
        atomicAdd(&hist[q.x], 1);
        atomicAdd(&hist[q.y], 1);
        atomicAdd(&hist[q.z], 1);
        atomicAdd(&hist[q.w], 1);
    } else {
        for (int k = 0; k < 4; ++k)
            if (e4 + k < E) atomicAdd(&hist[dst[e4 + k]], 1);
    }
}

// Exclusive scan hist[0..N) -> rowptr[0..N]; values cached in registers so
// phase 3 re-reads nothing from global. Single 1024-thread block.
__global__ __launch_bounds__(1024) void scan_kernel(
    const int* __restrict__ hist, int* __restrict__ rowptr, int N)
{
    __shared__ int part[1024];
    int tid = threadIdx.x;
    int lo = tid * SCAN_CHUNK;
    int vals[SCAN_CHUNK];

    if (lo + SCAN_CHUNK <= N) {
        #pragma unroll
        for (int k = 0; k < SCAN_CHUNK; k += 4) {
            int4 q = *(const int4*)&hist[lo + k];
            vals[k] = q.x; vals[k+1] = q.y; vals[k+2] = q.z; vals[k+3] = q.w;
        }
    } else {
        #pragma unroll
        for (int k = 0; k < SCAN_CHUNK; ++k)
            vals[k] = (lo + k < N) ? hist[lo + k] : 0;
    }
    int s = 0;
    #pragma unroll
    for (int k = 0; k < SCAN_CHUNK; ++k) s += vals[k];

    part[tid] = s;
    __syncthreads();
    for (int off = 1; off < 1024; off <<= 1) {
        int t = (tid >= off) ? part[tid - off] : 0;
        __syncthreads();
        part[tid] += t;
        __syncthreads();
    }

    int run = part[tid] - s;   // exclusive prefix of this chunk
    if (lo + SCAN_CHUNK <= N) {
        #pragma unroll
        for (int k = 0; k < SCAN_CHUNK; k += 4) {
            int4 q;
            q.x = run; run += vals[k];
            q.y = run; run += vals[k+1];
            q.z = run; run += vals[k+2];
            q.w = run; run += vals[k+3];
            *(int4*)&rowptr[lo + k] = q;
        }
    } else {
        #pragma unroll
        for (int k = 0; k < SCAN_CHUNK; ++k) {
            if (lo + k < N) rowptr[lo + k] = run;
            run += vals[k];
        }
    }
    if (tid == 1023) rowptr[N] = part[1023];
}

__global__ __launch_bounds__(256) void scatter_kernel(
    const int* __restrict__ src, const int* __restrict__ dst,
    const int* __restrict__ etype, const int* __restrict__ rowptr,
    int* __restrict__ cur, int2* __restrict__ es, int E)
{
    int e4 = (blockIdx.x * blockDim.x + threadIdx.x) * 4;
    if (e4 + 3 < E) {
        int4 d = *(const int4*)&dst[e4];
        int4 s = *(const int4*)&src[e4];
        int4 t = *(const int4*)&etype[e4];
        int p0 = rowptr[d.x] + atomicAdd(&cur[d.x], 1);
        int p1 = rowptr[d.y] + atomicAdd(&cur[d.y], 1);
        int p2 = rowptr[d.z] + atomicAdd(&cur[d.z], 1);
        int p3 = rowptr[d.w] + atomicAdd(&cur[d.w], 1);
        es[p0] = make_int2(s.x, t.x);
        es[p1] = make_int2(s.y, t.y);
        es[p2] = make_int2(s.z, t.z);
        es[p3] = make_int2(s.w, t.w);
    } else {
        for (int k = 0; k < 4; ++k) {
            int e = e4 + k;
            if (e < E) {
                int v = dst[e];
                int pos = rowptr[v] + atomicAdd(&cur[v], 1);
                es[pos] = make_int2(src[e], etype[e]);
            }
        }
    }
}

#define ACC(e, f, r) do {                                   \
    bool bi = (e).y < half_rel;                             \
    float cx = (f).x - (r).x, cy = (f).y - (r).y;           \
    aI.x += bi ? cx : 0.0f; aI.y += bi ? cy : 0.0f;         \
    aO.x += bi ? 0.0f : cx; aO.y += bi ? 0.0f : cy;         \
    cIl += bi ? 1 : 0;                                      \
} while (0)

__global__ __launch_bounds__(512) void node_fused_kernel(
    const float* __restrict__ n_feats,
    const float* __restrict__ r_feats,
    const int* __restrict__ rowptr,
    const int2* __restrict__ es,
    const float* __restrict__ W_I_w, const float* __restrict__ W_I_b,
    const float* __restrict__ W_O_w, const float* __restrict__ W_O_b,
    const float* __restrict__ W_R_w, const float* __restrict__ W_R_b,
    const int* __restrict__ num_rels,
    float* __restrict__ n_out, float* __restrict__ r_out,
    int N, int R, int nodeBlocks)
{
    __shared__ float WIp[DIM * WPAD];
    __shared__ float WOp[DIM * WPAD];
    __shared__ float xI[NPB][2][DIM];
    __shared__ float xO[NPB][2][DIM];

    int tid  = threadIdx.x;
    int wave = tid >> 6;
    int lane = tid & 63;

    if (blockIdx.x >= nodeBlocks) {
        // ---- relation rows: r_out = r_feats @ W_R^T + b_R ----
        for (int i = tid; i < DIM * DIM; i += 512) {
            int j = i >> 6, d = i & 63;          // consecutive tid -> consecutive d
            WIp[j * WPAD + d] = W_R_w[i];
        }
        int r = (blockIdx.x - nodeBlocks) * NPB + wave;
        if (r < R) xI[wave][0][lane] = r_feats[(size_t)r * DIM + lane];
        __syncthreads();
        if (r < R) {
            float sum = W_R_b[lane];
            #pragma unroll
            for (int d4 = 0; d4 < DIM; d4 += 4) {
                float4 w = *(const float4*)&WIp[lane * WPAD + d4];
                float4 x = *(const float4*)&xI[wave][0][d4];
                sum += w.x*x.x + w.y*x.y + w.z*x.z + w.w*x.w;
            }
            r_out[(size_t)r * DIM + lane] = sum;
        }
        return;
    }

    // ---- node blocks ----
    for (int i = tid; i < DIM * DIM; i += 512) {
        int j = i >> 6, d = i & 63;              // conflict-free stores
        WIp[j * WPAD + d] = W_I_w[i];
        WOp[j * WPAD + d] = W_O_w[i];
    }

    int h  = lane >> 5;     // half-wave: 0 -> even edges, 1 -> odd edges
    int fl = lane & 31;     // float2 index within the 64-feature row
    int v  = blockIdx.x * NPB + wave;
    int half_rel = num_rels[0] >> 1;

    const float2* nf2 = (const float2*)n_feats;
    const float2* rf2 = (const float2*)r_feats;

    float2 aI = make_float2(0.0f, 0.0f);
    float2 aO = make_float2(0.0f, 0.0f);
    int cIl = 0, lo = 0, deg = 0;
    if (v < N) { lo = rowptr[v]; deg = rowptr[v + 1] - lo; }
    int hi = lo + deg;

    int i = lo + h;
    // 4x unroll: edges i, i+2, i+4, i+6 in flight together
    for (; i + 6 < hi; i += 8) {
        int2 e0 = es[i];
        int2 e1 = es[i + 2];
        int2 e2 = es[i + 4];
        int2 e3 = es[i + 6];
        float2 f0 = nf2[(size_t)e0.x * 32 + fl];
        float2 r0 = rf2[(size_t)e0.y * 32 + fl];
        float2 f1 = nf2[(size_t)e1.x * 32 + fl];
        float2 r1 = rf2[(size_t)e1.y * 32 + fl];
        float2 f2 = nf2[(size_t)e2.x * 32 + fl];
        float2 r2 = rf2[(size_t)e2.y * 32 + fl];
        float2 f3 = nf2[(size_t)e3.x * 32 + fl];
        float2 r3 = rf2[(size_t)e3.y * 32 + fl];
        ACC(e0, f0, r0);
        ACC(e1, f1, r1);
        ACC(e2, f2, r2);
        ACC(e3, f3, r3);
    }
    for (; i < hi; i += 2) {
        int2 e0 = es[i];
        float2 f0 = nf2[(size_t)e0.x * 32 + fl];
        float2 r0 = rf2[(size_t)e0.y * 32 + fl];
        ACC(e0, f0, r0);
    }

    *(float2*)&xI[wave][h][2 * fl] = aI;
    *(float2*)&xO[wave][h][2 * fl] = aO;
    __syncthreads();   // weights + x staged

    // combine the two half-wave partials (per-wave private data; same-wave
    // LDS ordering is handled by compiler-inserted lgkmcnt waits)
    xI[wave][0][lane] += xI[wave][1][lane];
    xO[wave][0][lane] += xO[wave][1][lane];

    int cI = __shfl(cIl, 0) + __shfl(cIl, 32);
    if (v < N) {
        int cO = deg - cI;
        float sum = (float)cI * W_I_b[lane] + (float)cO * W_O_b[lane];
        #pragma unroll
        for (int d4 = 0; d4 < DIM; d4 += 4) {
            float4 wi = *(const float4*)&WIp[lane * WPAD + d4];
            float4 wo = *(const float4*)&WOp[lane * WPAD + d4];
            float4 xi = *(const float4*)&xI[wave][0][d4];
            float4 xo = *(const float4*)&xO[wave][0][d4];
            sum += wi.x*xi.x + wi.y*xi.y + wi.z*xi.z + wi.w*xi.w
                 + wo.x*xo.x + wo.y*xo.y + wo.z*xo.z + wo.w*xo.w;
        }
        n_out[(size_t)v * DIM + lane] = sum / (float)(deg > 1 ? deg : 1);
    }
}

extern "C" void kernel_launch(void* const* d_in, const int* in_sizes, int n_in,
                              void* d_out, int out_size, void* d_ws, size_t ws_size,
                              hipStream_t stream) {
    const float* n_feats  = (const float*)d_in[0];
    const float* r_feats  = (const float*)d_in[1];
    const float* W_I_w    = (const float*)d_in[2];
    const float* W_I_b    = (const float*)d_in[3];
    const float* W_O_w    = (const float*)d_in[4];
    const float* W_O_b    = (const float*)d_in[5];
    const float* W_R_w    = (const float*)d_in[6];
    const float* W_R_b    = (const float*)d_in[7];
    const int*   src      = (const int*)d_in[8];
    const int*   dst      = (const int*)d_in[9];
    const int*   etype    = (const int*)d_in[10];
    const int*   num_rels = (const int*)d_in[11];

    const int N = in_sizes[0] / DIM;
    const int R = in_sizes[1] / DIM;
    const int E = in_sizes[8];

    // ws layout: es [E int2] | hist [N] | cur [N] | rowptr [N+1]
    int2* es     = (int2*)d_ws;
    int*  hist   = (int*)(es + (size_t)E);
    int*  cur    = hist + N;
    int*  rowptr = cur + N;

    int zn = 2 * N;
    zero_int_kernel<<<(zn + 255) / 256, 256, 0, stream>>>(hist, zn);

    int eb = (E + 1023) / 1024;    // 4 edges per thread
    hist_kernel<<<eb, 256, 0, stream>>>(dst, hist, E);

    scan_kernel<<<1, 1024, 0, stream>>>(hist, rowptr, N);

    scatter_kernel<<<eb, 256, 0, stream>>>(src, dst, etype, rowptr, cur, es, E);

    float* n_out = (float*)d_out;
    float* r_out = n_out + (size_t)N * DIM;

    int nodeBlocks = (N + NPB - 1) / NPB;
    int relBlocks  = (R + NPB - 1) / NPB;
    node_fused_kernel<<<nodeBlocks + relBlocks, 512, 0, stream>>>(
        n_feats, r_feats, rowptr, es,
        W_I_w, W_I_b, W_O_w, W_O_b, W_R_w, W_R_b, num_rels,
        n_out, r_out, N, R, nodeBlocks);
}